// Round 3
// baseline (368.062 us; speedup 1.0000x reference)
//
#include <hip/hip_runtime.h>

// Problem constants
#define CC   128      // input channels
#define SB   16384    // T*H*W per batch

typedef _Float16 half4_t __attribute__((ext_vector_type(4)));

// workspace byte offsets (total use: 41,940,992 bytes; known-safe budget 50.6MB)
#define WT_OFF    0u          // 24576 floats, WT[c*192 + slot] (phi|theta|rho)
#define BIAS_OFF  98304u      // 192 floats
#define CM_OFF    99072u      // 8*1024 floats
#define SUME_OFF  131840u     // 512 floats
#define RINV_OFF  133888u     // 512 floats
#define ABT_OFF   135936u     // 8*4096 floats, ABt[b][n][m]
#define E_OFF     267264u     // 8*64*16384 halves  exp(theta)
#define V_OFF     17044480u   // 8*64*16384 halves  V (softmax over channels)
#define PART_OFF  33821696u   // 512*4096 floats    per-block AB partials (8MB)

// ---------------------------------------------------------------- k0: setup
__global__ void k0_setup(const float* __restrict__ cond,
                         const float* __restrict__ W_phi, const float* __restrict__ b_phi,
                         const float* __restrict__ W_theta, const float* __restrict__ b_theta,
                         const float* __restrict__ W_rho, const float* __restrict__ b_rho,
                         const float* __restrict__ W1, const float* __restrict__ b1,
                         const float* __restrict__ W2, const float* __restrict__ b2,
                         char* __restrict__ wsc) {
  __shared__ float sc[64], sh1[64], red[256];
  int t = threadIdx.x, bid = blockIdx.x;
  if (bid < 8) {
    int b = bid;
    if (t < 64) sc[t] = cond[b*64 + t];
    __syncthreads();
    if (t < 64) {
      float acc = b1[t];
      for (int k = 0; k < 64; ++k) acc += sc[k] * W1[t*64 + k];
      sh1[t] = fmaxf(acc, 0.f);
    }
    __syncthreads();
    float ev[4]; float ps = 0.f;
    #pragma unroll
    for (int q = 0; q < 4; ++q) {
      int o = q*256 + t;
      float acc = b2[o];
      for (int k = 0; k < 64; ++k) acc += sh1[k] * W2[o*64 + k];
      ev[q] = __expf(fmaxf(acc, 0.f));
      ps += ev[q];
    }
    red[t] = ps; __syncthreads();
    for (int s = 128; s > 0; s >>= 1) { if (t < s) red[t] += red[t+s]; __syncthreads(); }
    float inv = 1.f / red[0];
    float* cm = (float*)(wsc + CM_OFF);
    #pragma unroll
    for (int q = 0; q < 4; ++q) cm[b*1024 + q*256 + t] = ev[q] * inv;
  } else {
    int r = bid - 8;
    float* wt = (float*)(wsc + WT_OFF);
    for (int i = r*256 + t; i < 24576; i += 2048) {
      int c = i / 192, slot = i % 192;
      float v;
      if (slot < 64)       v = W_phi[slot*128 + c];
      else if (slot < 128) v = W_theta[(slot-64)*128 + c];
      else                 v = W_rho[(slot-128)*128 + c];
      wt[i] = v;
    }
    if (r == 0 && t < 192) {
      float* bias = (float*)(wsc + BIAS_OFF);
      bias[t] = (t < 64) ? b_phi[t] : (t < 128 ? b_theta[t-64] : b_rho[t-128]);
    }
    if (r == 1) {
      float* se = (float*)(wsc + SUME_OFF);
      for (int i = t; i < 512; i += 256) se[i] = 0.f;
    }
  }
}

// ----------------------------------------------- kA: theta+phi convs + AB partials
// grid 512 = 8b * 64 chunks(256 pos). lane = position, acc reg = output channel.
// Weights are lane-uniform -> s_load into SGPRs -> zero VMEM-pipe cost
// (round-2 lesson: redundant vector weight loads saturated the VMEM pipe).
__global__ __launch_bounds__(256) void kA_phitheta(
    const float* __restrict__ x,
    const float* __restrict__ wt,    // [c][192]
    const float* __restrict__ bias,  // [192]
    const float* __restrict__ cm,    // [8][1024]
    float* __restrict__ sumE,        // [8][64], pre-zeroed
    _Float16* __restrict__ e_ws,     // [8*64][16384]
    float* __restrict__ part) {      // [512][4096]
  __shared__ float aC[64*68];        // A subchunk tile  [m][64 pos], padded
  __shared__ _Float16 eC[64*264];    // ecm full tile    [n][256 pos], padded

  int t = threadIdx.x;
  int lane = t & 63, wv = t >> 6;
  int bid = blockIdx.x;
  int b = bid >> 6, chunk = bid & 63;
  int s = chunk*256 + wv*64 + lane;
  const float* xb = x + (size_t)b*CC*SB + s;

  // ---- pass 1: theta conv (64 accs, weights from SGPRs) ----
  float acc[64];
  #pragma unroll
  for (int o = 0; o < 64; ++o) acc[o] = 0.f;
  for (int c = 0; c < CC; ++c) {
    float xv = xb[(size_t)c*SB];
    const float* wr = wt + c*192 + 64;   // uniform -> s_load
    #pragma unroll
    for (int o = 0; o < 64; ++o) acc[o] = fmaf(wr[o], xv, acc[o]);
  }
  // ---- epilogue 1: e = exp(theta+b); store fp16; sumE butterfly; ecm -> LDS ----
  float cmv = cm[b*1024 + (s & 1023)];
  {
    const float* bb = bias + 64;
    float mysum = 0.f;
    #pragma unroll
    for (int o = 0; o < 64; ++o) {
      float e = __expf(acc[o] + bb[o]);
      e_ws[(size_t)(b*64 + o)*SB + s] = (_Float16)e;
      eC[o*264 + wv*64 + lane] = (_Float16)(e * cmv);
      float r = e;
      r += __shfl_xor(r, 32); r += __shfl_xor(r, 16); r += __shfl_xor(r, 8);
      r += __shfl_xor(r, 4);  r += __shfl_xor(r, 2);  r += __shfl_xor(r, 1);
      if (lane == o) mysum = r;           // lane o keeps channel o's wave-sum
    }
    atomicAdd(&sumE[b*64 + lane], mysum); // one coalesced 64-lane atomic
  }

  // ---- pass 2: phi conv (reuse acc regs) ----
  #pragma unroll
  for (int o = 0; o < 64; ++o) acc[o] = 0.f;
  for (int c = 0; c < CC; ++c) {
    float xv = xb[(size_t)c*SB];
    const float* wr = wt + c*192;        // uniform -> s_load
    #pragma unroll
    for (int o = 0; o < 64; ++o) acc[o] = fmaf(wr[o], xv, acc[o]);
  }
  {
    const float* bb = bias;
    #pragma unroll
    for (int o = 0; o < 64; ++o) acc[o] += bb[o];
  }
  __syncthreads();                        // eC complete

  // ---- AB rank update: ab[m][n] += A[m][s]*ecm[n][s] over this block's 256 pos ----
  float ab[4][4];
  #pragma unroll
  for (int i = 0; i < 4; ++i)
    #pragma unroll
    for (int j = 0; j < 4; ++j) ab[i][j] = 0.f;
  int ti = t >> 4, tj = t & 15;
  int m0 = ti*4, n0 = tj*4;
  for (int v = 0; v < 4; ++v) {
    if (wv == v) {
      #pragma unroll
      for (int o = 0; o < 64; ++o) aC[o*68 + lane] = acc[o];  // conflict-free (lane-linear)
    }
    __syncthreads();
    for (int k0 = 0; k0 < 64; k0 += 4) {
      float fa[4][4];
      #pragma unroll
      for (int i = 0; i < 4; ++i) *(float4*)fa[i] = *(float4*)&aC[(m0+i)*68 + k0];
      float fe[4][4];
      #pragma unroll
      for (int j = 0; j < 4; ++j) {
        half4_t h = *(half4_t*)&eC[(n0+j)*264 + v*64 + k0];
        fe[j][0] = (float)h[0]; fe[j][1] = (float)h[1];
        fe[j][2] = (float)h[2]; fe[j][3] = (float)h[3];
      }
      #pragma unroll
      for (int kk = 0; kk < 4; ++kk)
        #pragma unroll
        for (int i = 0; i < 4; ++i)
          #pragma unroll
          for (int j = 0; j < 4; ++j)
            ab[i][j] = fmaf(fa[i][kk], fe[j][kk], ab[i][j]);
    }
    __syncthreads();                      // before wave v+1 overwrites aC
  }
  float* pp = part + (size_t)bid*4096;
  #pragma unroll
  for (int i = 0; i < 4; ++i) {
    float w4[4] = {ab[i][0], ab[i][1], ab[i][2], ab[i][3]};
    *(float4*)&pp[(m0+i)*64 + n0] = *(float4*)w4;
  }
}

// ----------------------------------------------- kR: rho conv + channel softmax -> V
__global__ __launch_bounds__(256) void kR_rho(
    const float* __restrict__ x,
    const float* __restrict__ wt,
    const float* __restrict__ bias,
    _Float16* __restrict__ v_ws) {
  int t = threadIdx.x;
  int lane = t & 63, wv = t >> 6;
  int bid = blockIdx.x;
  int b = bid >> 6, chunk = bid & 63;
  int s = chunk*256 + wv*64 + lane;
  const float* xb = x + (size_t)b*CC*SB + s;

  float acc[64];
  #pragma unroll
  for (int o = 0; o < 64; ++o) acc[o] = 0.f;
  for (int c = 0; c < CC; ++c) {
    float xv = xb[(size_t)c*SB];
    const float* wr = wt + c*192 + 128;  // uniform -> s_load
    #pragma unroll
    for (int o = 0; o < 64; ++o) acc[o] = fmaf(wr[o], xv, acc[o]);
  }
  const float* bb = bias + 128;
  float ssum = 0.f;
  #pragma unroll
  for (int o = 0; o < 64; ++o) { acc[o] = __expf(acc[o] + bb[o]); ssum += acc[o]; }
  float inv = 1.f / ssum;                // per-lane (per-position) channel softmax
  #pragma unroll
  for (int o = 0; o < 64; ++o)
    v_ws[(size_t)(b*64 + o)*SB + s] = (_Float16)(acc[o] * inv);
}

// ---------------------------------------------- k2: reduce AB partials, rinv
__global__ void k2_reduce(const float* __restrict__ part,
                          const float* __restrict__ sumE,
                          float* __restrict__ abt,
                          float* __restrict__ rinv) {
  int idx = blockIdx.x * 256 + threadIdx.x;
  int b = idx >> 12, mn = idx & 4095;
  int m = mn >> 6, n = mn & 63;
  const float* p = part + (size_t)b*64*4096 + mn;
  float s = 0.f;
  #pragma unroll 4
  for (int k = 0; k < 64; ++k) s += p[(size_t)k * 4096];
  abt[b*4096 + n*64 + m] = s / sumE[b*64 + n];   // n-major for k3
  if (idx < 512) rinv[idx] = 1.f / sumE[idx];
}

// ---------------------------------------------------------------- k3: Z GEMM
// grid 2048 = b(8) * tt(16) * hwchunk(16); Z[m][hw] = sum_n ABt[n][m]*V[n][hw]
__global__ __launch_bounds__(256) void k3_z(const float* __restrict__ abt,
                                            const _Float16* __restrict__ v_ws,
                                            float* __restrict__ zout) {
  __shared__ float ABl[64*66];
  __shared__ float Vl[64*68];
  int t = threadIdx.x, bid = blockIdx.x;
  int b = bid >> 8, tt = (bid >> 4) & 15, hwc = bid & 15;
  #pragma unroll
  for (int q = 0; q < 16; ++q) {
    int fid = q*256 + t;
    ABl[(fid >> 6)*66 + (fid & 63)] = abt[b*4096 + fid];
  }
  int ti = t >> 4, tj = t & 15;
  int m0 = ti*4, h0 = tj*4;
  size_t sbase = (size_t)tt*1024 + hwc*64;
  #pragma unroll
  for (int q = 0; q < 4; ++q) {
    int fid = q*256 + t;
    int n = fid >> 4, h4 = (fid & 15) << 2;
    half4_t hv = *(const half4_t*)(v_ws + (size_t)(b*64+n)*SB + sbase + h4);
    Vl[n*68 + h4 + 0] = (float)hv[0];
    Vl[n*68 + h4 + 1] = (float)hv[1];
    Vl[n*68 + h4 + 2] = (float)hv[2];
    Vl[n*68 + h4 + 3] = (float)hv[3];
  }
  __syncthreads();
  float acc[4][4];
  #pragma unroll
  for (int i = 0; i < 4; ++i)
    #pragma unroll
    for (int j = 0; j < 4; ++j) acc[i][j] = 0.f;
  #pragma unroll 4
  for (int k = 0; k < 64; ++k) {
    float av[4], vv[4];
    *(float4*)av = *(float4*)&ABl[k*66 + m0];
    *(float4*)vv = *(float4*)&Vl[k*68 + h0];
    #pragma unroll
    for (int i = 0; i < 4; ++i)
      #pragma unroll
      for (int j = 0; j < 4; ++j) acc[i][j] += av[i] * vv[j];
  }
  #pragma unroll
  for (int i = 0; i < 4; ++i) {
    float w[4] = {acc[i][0], acc[i][1], acc[i][2], acc[i][3]};
    *(float4*)(zout + (size_t)(b*64 + m0 + i)*SB + sbase + h0) = *(float4*)w;
  }
}

// --------------------------------------------------- k4: attn = e*V/sumE, transposed
__global__ void k4_attn(const _Float16* __restrict__ e_ws,
                        const _Float16* __restrict__ v_ws,
                        const float* __restrict__ rinv,
                        float* __restrict__ out) {
  int t = threadIdx.x, bid = blockIdx.x;
  int b = bid >> 6, n = bid & 63;
  int hw0 = t*4;
  float ri = rinv[b*64 + n];
  size_t ibase = (size_t)(b*64 + n)*SB + hw0;
  float tv[16][4];
  #pragma unroll
  for (int k = 0; k < 16; ++k) {
    half4_t e4 = *(const half4_t*)(e_ws + ibase + k*1024);
    half4_t v4 = *(const half4_t*)(v_ws + ibase + k*1024);
    #pragma unroll
    for (int j = 0; j < 4; ++j) tv[k][j] = (float)e4[j] * (float)v4[j] * ri;
  }
  float* ob = out + 8388608 + ((size_t)(b*64 + n)*1024 + hw0)*16;
  #pragma unroll
  for (int h = 0; h < 4; ++h)
    #pragma unroll
    for (int q = 0; q < 4; ++q) {
      float w[4] = {tv[q*4+0][h], tv[q*4+1][h], tv[q*4+2][h], tv[q*4+3][h]};
      *(float4*)(ob + h*16 + q*4) = *(float4*)w;
    }
}

extern "C" void kernel_launch(void* const* d_in, const int* in_sizes, int n_in,
                              void* d_out, int out_size, void* d_ws, size_t ws_size,
                              hipStream_t stream) {
  const float* input   = (const float*)d_in[0];
  const float* cond    = (const float*)d_in[1];
  const float* W_phi   = (const float*)d_in[2];
  const float* b_phi   = (const float*)d_in[3];
  const float* W_theta = (const float*)d_in[4];
  const float* b_theta = (const float*)d_in[5];
  const float* W_rho   = (const float*)d_in[6];
  const float* b_rho   = (const float*)d_in[7];
  const float* W1      = (const float*)d_in[8];
  const float* b1      = (const float*)d_in[9];
  const float* W2      = (const float*)d_in[10];
  const float* b2      = (const float*)d_in[11];
  char* wsc = (char*)d_ws;
  float* out = (float*)d_out;

  const float* wt   = (const float*)(wsc + WT_OFF);
  const float* bias = (const float*)(wsc + BIAS_OFF);
  const float* cm   = (const float*)(wsc + CM_OFF);
  float* sumE  = (float*)(wsc + SUME_OFF);
  float* rinv  = (float*)(wsc + RINV_OFF);
  float* abt   = (float*)(wsc + ABT_OFF);
  _Float16* e_ws = (_Float16*)(wsc + E_OFF);
  _Float16* v_ws = (_Float16*)(wsc + V_OFF);
  float* part  = (float*)(wsc + PART_OFF);

  hipLaunchKernelGGL(k0_setup, dim3(16), dim3(256), 0, stream,
                     cond, W_phi, b_phi, W_theta, b_theta, W_rho, b_rho,
                     W1, b1, W2, b2, wsc);
  hipLaunchKernelGGL(kA_phitheta, dim3(512), dim3(256), 0, stream,
                     input, wt, bias, cm, sumE, e_ws, part);
  hipLaunchKernelGGL(kR_rho, dim3(512), dim3(256), 0, stream,
                     input, wt, bias, v_ws);
  hipLaunchKernelGGL(k2_reduce, dim3(128), dim3(256), 0, stream,
                     part, sumE, abt, rinv);
  hipLaunchKernelGGL(k3_z, dim3(2048), dim3(256), 0, stream, abt, v_ws, out);
  hipLaunchKernelGGL(k4_attn, dim3(512), dim3(256), 0, stream, e_ws, v_ws, rinv, out);
}

// Round 4
// 227.886 us; speedup vs baseline: 1.6151x; 1.6151x over previous
//
#include <hip/hip_runtime.h>

#define CC 128
#define SB 16384   // T*H*W

typedef _Float16 half4_t __attribute__((ext_vector_type(4)));
typedef _Float16 half8_t __attribute__((ext_vector_type(8)));
typedef float    f32x4  __attribute__((ext_vector_type(4)));

// ---- workspace map (total 50,593,792 B <= known-safe 50,598,912) ----
#define WH_OFF   0u         // 3*64*128 fp16 weights [set][m][k]  (dead after kC)
#define ABH_OFF  0u         // 8*64*64 fp16 ABt*1024 (k2 writes, aliases WH -- WH dead)
#define BIAS_OFF 49152u     // 192 f32
#define CM_OFF   50176u     // 8*1024 f32 Cm
#define SUME_OFF 82944u     // 512 f32 (zeroed by k0, atomicAdd by kC)
#define XT_OFF   262144u    // 8*16384 rows of 256B: fp16 x-transposed [b][s][c0..127]
                            // P_t (=e*V fp16 [s][n0..63]) aliases bytes [128,256) of each
                            // row -- safe: only the block owning (b,s) reads XT row s
                            // (staged to LDS before its own P writes).
#define VT_OFF   33816576u  // 8*16384*64 fp16 V [s][n]
// AB per-block partials (1024*4096 f32 = 16.8MB) live in d_out's attn region
// (d_out+8388608): written by kC, read by k2, then fully overwritten by k4.

// ---------------------------------------------------------------- k0: setup
__global__ void k0_setup(const float* __restrict__ cond,
                         const float* __restrict__ W_phi, const float* __restrict__ b_phi,
                         const float* __restrict__ W_theta, const float* __restrict__ b_theta,
                         const float* __restrict__ W_rho, const float* __restrict__ b_rho,
                         const float* __restrict__ W1, const float* __restrict__ b1,
                         const float* __restrict__ W2, const float* __restrict__ b2,
                         char* __restrict__ wsc) {
  __shared__ float sc[64], sh1[64], red[256];
  int t = threadIdx.x, bid = blockIdx.x;
  if (bid < 8) {
    int b = bid;
    if (t < 64) sc[t] = cond[b*64 + t];
    __syncthreads();
    if (t < 64) {
      float acc = b1[t];
      for (int k = 0; k < 64; ++k) acc += sc[k] * W1[t*64 + k];
      sh1[t] = fmaxf(acc, 0.f);
    }
    __syncthreads();
    float ev[4]; float ps = 0.f;
    #pragma unroll
    for (int q = 0; q < 4; ++q) {
      int o = q*256 + t;
      float acc = b2[o];
      for (int k = 0; k < 64; ++k) acc += sh1[k] * W2[o*64 + k];
      ev[q] = __expf(fmaxf(acc, 0.f));
      ps += ev[q];
    }
    red[t] = ps; __syncthreads();
    for (int s = 128; s > 0; s >>= 1) { if (t < s) red[t] += red[t+s]; __syncthreads(); }
    float inv = 1.f / red[0];
    float* cm = (float*)(wsc + CM_OFF);
    #pragma unroll
    for (int q = 0; q < 4; ++q) cm[b*1024 + q*256 + t] = ev[q] * inv;
  } else {
    int r = bid - 8;
    _Float16* wh = (_Float16*)(wsc + WH_OFF);
    for (int i = r*256 + t; i < 24576; i += 2048) {
      int set = i >> 13, mk = i & 8191;
      const float* W = (set == 0) ? W_phi : (set == 1 ? W_theta : W_rho);
      wh[i] = (_Float16)W[mk];       // all W_* are [64][128] row-major already
    }
    if (r == 0 && t < 192) {
      float* bias = (float*)(wsc + BIAS_OFF);
      bias[t] = (t < 64) ? b_phi[t] : (t < 128 ? b_theta[t-64] : b_rho[t-128]);
    }
    if (r == 1) {
      float* se = (float*)(wsc + SUME_OFF);
      for (int i = t; i < 512; i += 256) se[i] = 0.f;
    }
  }
}

// ------------------------------------------- kT: x fp32 [c][s] -> xt fp16 [s][c]
// grid 1024 = 8b * 128 chunks(128 s). LDS tile transpose; writes 256B-rows coalesced.
__global__ __launch_bounds__(256, 2) void kT_transpose(const float* __restrict__ x,
                                                       _Float16* __restrict__ xt) {
  __shared__ float Xs[128*133];      // pad 133: phase-2 c8-stride 8*133 % 32 = 8 (4-way max)
  int t = threadIdx.x, bid = blockIdx.x;
  int b = bid >> 7, chunk = bid & 127;
  int s0 = chunk * 128;
  const float* xb = x + (size_t)b*CC*SB + s0;
  #pragma unroll
  for (int r = 0; r < 16; ++r) {
    int fid = r*256 + t;             // 4096 float4-chunks
    int c = fid >> 5, s4 = (fid & 31) << 2;
    *(float4*)&Xs[c*133 + s4] = *(const float4*)(xb + (size_t)c*SB + s4);
  }
  __syncthreads();
  int c8 = t & 15, sl = t >> 4;
  _Float16* xo = xt + ((size_t)b*SB + s0)*128 + c8*8;
  #pragma unroll
  for (int it = 0; it < 8; ++it) {
    int s = it*16 + sl;
    half8_t h;
    #pragma unroll
    for (int i = 0; i < 8; ++i) h[i] = (_Float16)Xs[(c8*8 + i)*133 + s];
    *(half8_t*)(xo + (size_t)s*128) = h;   // lanes: 16 c8 x 16B contig per s -> 1KB/instr
  }
}

// ------------------------------------- kC: 3 convs (MFMA) + epilogues + AB partials
// grid 1024 = 8b * 128 chunks(128 s), 4 waves. Wave: 32 pos (2 n-tiles), all 64 outs.
// Frag maps (m89/m120-verified): A[m=ln][k=q*8+j], B[k=q*8+j][n=ln], D[m=q*4+r][n=ln].
__global__ __launch_bounds__(256, 2) void kC_main(
    const _Float16* __restrict__ xt, const _Float16* __restrict__ wh,
    const float* __restrict__ bias, const float* __restrict__ cm,
    float* __restrict__ sumE, _Float16* __restrict__ vt,
    char* __restrict__ ptb,            // byte base of XT region (P rows at +128)
    float* __restrict__ part) {
  __shared__ _Float16 Xt_l[128*136];   // [s][c], pad 136: conflict-free b128 frags
  __shared__ _Float16 A_l[64*136];     // phi result [m][s]
  __shared__ _Float16 E_l[64*136];     // e*cm [n][s]
  __shared__ float se_l[256];          // per-wave sumE partials [wv][64]

  int t = threadIdx.x;
  int lane = t & 63, wv = t >> 6, ln = lane & 15, q = lane >> 4;
  int bid = blockIdx.x, b = bid >> 7, chunk = bid & 127;
  int s0 = chunk * 128;

  // stage Xt tile (fp16, 32KB): 1KB contiguous per instr
  #pragma unroll
  for (int r = 0; r < 8; ++r) {
    int fid = r*256 + t;
    int s = fid >> 4, c16 = fid & 15;
    *(half8_t*)&Xt_l[s*136 + c16*8] =
        *(const half8_t*)(xt + ((size_t)b*SB + s0 + s)*128 + c16*8);
  }
  __syncthreads();

  // B-fragments for this wave's 32 positions (kept in regs across all 3 sets)
  half8_t bf[2][4];
  int myp = wv * 32;
  #pragma unroll
  for (int nt = 0; nt < 2; ++nt)
    #pragma unroll
    for (int kk = 0; kk < 4; ++kk)
      bf[nt][kk] = *(half8_t*)&Xt_l[(myp + nt*16 + ln)*136 + kk*32 + q*8];

  int gsl[2] = { s0 + myp + ln, s0 + myp + 16 + ln };
  float cmv[2] = { cm[b*1024 + (gsl[0] & 1023)], cm[b*1024 + (gsl[1] & 1023)] };

  half8_t af[4][4];
  f32x4 d[4][2];
  float ev[4][2][4];

  auto conv = [&](int setoff) {
    #pragma unroll
    for (int mt = 0; mt < 4; ++mt)
      #pragma unroll
      for (int kk = 0; kk < 4; ++kk)
        af[mt][kk] = *(const half8_t*)(wh + setoff + (mt*16 + ln)*128 + kk*32 + q*8);
    #pragma unroll
    for (int mt = 0; mt < 4; ++mt)
      #pragma unroll
      for (int nt = 0; nt < 2; ++nt)
        d[mt][nt] = (f32x4){0.f, 0.f, 0.f, 0.f};
    #pragma unroll
    for (int kk = 0; kk < 4; ++kk)
      #pragma unroll
      for (int mt = 0; mt < 4; ++mt)
        #pragma unroll
        for (int nt = 0; nt < 2; ++nt)
          d[mt][nt] = __builtin_amdgcn_mfma_f32_16x16x32_f16(af[mt][kk], bf[nt][kk],
                                                             d[mt][nt], 0, 0, 0);
  };

  // ---- set 0: phi -> A_l[m][s] fp16 ----
  conv(0);
  #pragma unroll
  for (int mt = 0; mt < 4; ++mt) {
    float bv[4]; *(float4*)bv = *(const float4*)(bias + mt*16 + q*4);
    #pragma unroll
    for (int nt = 0; nt < 2; ++nt)
      #pragma unroll
      for (int r = 0; r < 4; ++r)
        A_l[(mt*16 + q*4 + r)*136 + myp + nt*16 + ln] = (_Float16)(d[mt][nt][r] + bv[r]);
  }

  // ---- set 1: theta -> e (regs), ec -> E_l, sumE partials ----
  conv(8192);
  float sp[4][4];
  #pragma unroll
  for (int mt = 0; mt < 4; ++mt) {
    float bv[4]; *(float4*)bv = *(const float4*)(bias + 64 + mt*16 + q*4);
    #pragma unroll
    for (int r = 0; r < 4; ++r) {
      #pragma unroll
      for (int nt = 0; nt < 2; ++nt) {
        float e = __expf(d[mt][nt][r] + bv[r]);
        ev[mt][nt][r] = e;
        E_l[(mt*16 + q*4 + r)*136 + myp + nt*16 + ln] = (_Float16)(e * cmv[nt]);
      }
      sp[mt][r] = ev[mt][0][r] + ev[mt][1][r];
    }
  }
  #pragma unroll
  for (int mt = 0; mt < 4; ++mt)
    #pragma unroll
    for (int r = 0; r < 4; ++r) {
      float v = sp[mt][r];
      v += __shfl_xor(v, 1); v += __shfl_xor(v, 2);
      v += __shfl_xor(v, 4); v += __shfl_xor(v, 8);
      sp[mt][r] = v;          // sum over the 16 positions of this n-tile pair
    }
  if (ln == 0) {
    #pragma unroll
    for (int mt = 0; mt < 4; ++mt)
      #pragma unroll
      for (int r = 0; r < 4; ++r)
        se_l[wv*64 + mt*16 + q*4 + r] = sp[mt][r];
  }

  // ---- set 2: rho -> V (channel softmax), write V_t and P_t = e*V ----
  conv(16384);
  #pragma unroll
  for (int mt = 0; mt < 4; ++mt) {
    float bv[4]; *(float4*)bv = *(const float4*)(bias + 128 + mt*16 + q*4);
    #pragma unroll
    for (int nt = 0; nt < 2; ++nt)
      #pragma unroll
      for (int r = 0; r < 4; ++r)
        d[mt][nt][r] = __expf(d[mt][nt][r] + bv[r]);
  }
  float cs[2] = {0.f, 0.f};
  #pragma unroll
  for (int mt = 0; mt < 4; ++mt)
    #pragma unroll
    for (int nt = 0; nt < 2; ++nt)
      #pragma unroll
      for (int r = 0; r < 4; ++r) cs[nt] += d[mt][nt][r];
  #pragma unroll
  for (int nt = 0; nt < 2; ++nt) {            // sum over 4 quads -> all 64 channels
    cs[nt] += __shfl_xor(cs[nt], 16);
    cs[nt] += __shfl_xor(cs[nt], 32);
    cs[nt] = 1.f / cs[nt];
  }
  #pragma unroll
  for (int nt = 0; nt < 2; ++nt) {
    size_t grow = (size_t)b*SB + gsl[nt];
    _Float16* vrow = vt + grow*64;
    char* prow = ptb + grow*256 + 128;
    #pragma unroll
    for (int mt = 0; mt < 4; ++mt) {
      half4_t hv, hp;
      #pragma unroll
      for (int r = 0; r < 4; ++r) {
        float vv = d[mt][nt][r] * cs[nt];
        hv[r] = (_Float16)vv;
        hp[r] = (_Float16)(vv * ev[mt][nt][r]);
      }
      *(half4_t*)(vrow + mt*16 + q*4) = hv;
      *(half4_t*)(prow + (size_t)(mt*16 + q*4)*2) = hp;
    }
  }
  __syncthreads();                             // A_l, E_l, se_l complete

  if (t < 64) {
    float ssum = se_l[t] + se_l[64+t] + se_l[128+t] + se_l[192+t];
    atomicAdd(&sumE[b*64 + t], ssum);
  }

  // ---- AB rank-128 update via MFMA: AB[m][n] += A[m][s] * ec[n][s] ----
  f32x4 dab[4];
  #pragma unroll
  for (int n2 = 0; n2 < 4; ++n2) dab[n2] = (f32x4){0.f, 0.f, 0.f, 0.f};
  #pragma unroll
  for (int kk = 0; kk < 4; ++kk) {
    half8_t aab = *(half8_t*)&A_l[(wv*16 + ln)*136 + kk*32 + q*8];
    #pragma unroll
    for (int n2 = 0; n2 < 4; ++n2) {
      half8_t bab = *(half8_t*)&E_l[(n2*16 + ln)*136 + kk*32 + q*8];
      dab[n2] = __builtin_amdgcn_mfma_f32_16x16x32_f16(aab, bab, dab[n2], 0, 0, 0);
    }
  }
  float* pp = part + (size_t)bid*4096;
  #pragma unroll
  for (int n2 = 0; n2 < 4; ++n2)
    #pragma unroll
    for (int r = 0; r < 4; ++r)
      pp[(wv*16 + q*4 + r)*64 + n2*16 + ln] = dab[n2][r];
}

// ---------------- k2: reduce AB partials, scale 1024/sumE, fp16 [b][m][n]
__global__ void k2_reduce(const float* __restrict__ part, const float* __restrict__ sumE,
                          _Float16* __restrict__ abh) {
  int idx = blockIdx.x*256 + threadIdx.x;      // 32768
  int b = idx >> 12, mn = idx & 4095, n = mn & 63;
  const float* p = part + (size_t)b*128*4096 + mn;
  float s = 0.f;
  #pragma unroll 4
  for (int k = 0; k < 128; ++k) s += p[(size_t)k*4096];
  // x1024: keeps fp16 values well clear of denormals (AB ~ 2e-4); k3 undoes it
  abh[idx] = (_Float16)(s * (1024.f / sumE[b*64 + n]));
}

// ---------------------------------------------------------------- k3: Z GEMM (MFMA)
// grid 512 = 8b * 64 chunks(256 s). Z[m][s] = sum_n ABt[m][n] * V[n][s].
__global__ __launch_bounds__(256) void k3_z(const _Float16* __restrict__ abh,
                                            const _Float16* __restrict__ vt,
                                            float* __restrict__ zout) {
  __shared__ _Float16 Ah[64*72];
  int t = threadIdx.x;
  int lane = t & 63, wv = t >> 6, ln = lane & 15, q = lane >> 4;
  int bid = blockIdx.x, b = bid >> 6, chunk = bid & 63;
  int s0 = chunk * 256;
  #pragma unroll
  for (int r = 0; r < 2; ++r) {
    int fid = r*256 + t;
    int m = fid >> 3, n8 = fid & 7;
    *(half8_t*)&Ah[m*72 + n8*8] = *(const half8_t*)(abh + b*4096 + m*64 + n8*8);
  }
  __syncthreads();
  half8_t a8[4][2];
  #pragma unroll
  for (int mt = 0; mt < 4; ++mt)
    #pragma unroll
    for (int kk = 0; kk < 2; ++kk)
      a8[mt][kk] = *(half8_t*)&Ah[(mt*16 + ln)*72 + kk*32 + q*8];
  int sw = s0 + wv*64;
  #pragma unroll
  for (int nt = 0; nt < 4; ++nt) {
    int sb = sw + nt*16 + ln;
    const _Float16* vrow = vt + ((size_t)b*SB + sb)*64;
    half8_t b8[2];
    b8[0] = *(const half8_t*)(vrow + q*8);
    b8[1] = *(const half8_t*)(vrow + 32 + q*8);
    f32x4 dz[4];
    #pragma unroll
    for (int mt = 0; mt < 4; ++mt) dz[mt] = (f32x4){0.f, 0.f, 0.f, 0.f};
    #pragma unroll
    for (int kk = 0; kk < 2; ++kk)
      #pragma unroll
      for (int mt = 0; mt < 4; ++mt)
        dz[mt] = __builtin_amdgcn_mfma_f32_16x16x32_f16(a8[mt][kk], b8[kk], dz[mt], 0, 0, 0);
    #pragma unroll
    for (int mt = 0; mt < 4; ++mt)
      #pragma unroll
      for (int r = 0; r < 4; ++r)
        zout[((size_t)(b*64 + mt*16 + q*4 + r))*SB + sb] = dz[mt][r] * (1.f/1024.f);
  }
}

// ------------------------------- k4: attn[n][hw][t] = P[s][n] / sumE[n], t-innermost
// grid 512 = 8b * 64 hw-blocks(16 hw). LDS transpose: rows=s(16t x 16hw), cols=n.
__global__ __launch_bounds__(256) void k4_attn(const char* __restrict__ ptb,
                                               const float* __restrict__ sumE,
                                               float* __restrict__ outA) {
  __shared__ _Float16 P_l[256*72];
  int t = threadIdx.x, bid = blockIdx.x;
  int b = bid >> 6, hw0 = (bid & 63) * 16;
  int st = t >> 4, h = t & 15;
  int s = st*1024 + hw0 + h;
  const char* prow = ptb + ((size_t)b*SB + s)*256 + 128;
  #pragma unroll
  for (int c8 = 0; c8 < 8; ++c8)
    *(half8_t*)&P_l[t*72 + c8*8] = *(const half8_t*)(prow + c8*16);
  __syncthreads();
  int n = t >> 2, oc = t & 3;
  float ri = 1.f / sumE[b*64 + n];
  float* orow = outA + 8388608 + (size_t)(b*64 + n)*SB + hw0*16;
  #pragma unroll
  for (int i = 0; i < 16; ++i) {
    int j = oc*64 + i*4;
    int hh = j >> 4, stb = j & 15;
    float w[4];
    #pragma unroll
    for (int r = 0; r < 4; ++r)
      w[r] = (float)P_l[((stb + r)*16 + hh)*72 + n] * ri;
    *(float4*)(orow + j) = *(float4*)w;
  }
}

extern "C" void kernel_launch(void* const* d_in, const int* in_sizes, int n_in,
                              void* d_out, int out_size, void* d_ws, size_t ws_size,
                              hipStream_t stream) {
  const float* input   = (const float*)d_in[0];
  const float* cond    = (const float*)d_in[1];
  const float* W_phi   = (const float*)d_in[2];
  const float* b_phi   = (const float*)d_in[3];
  const float* W_theta = (const float*)d_in[4];
  const float* b_theta = (const float*)d_in[5];
  const float* W_rho   = (const float*)d_in[6];
  const float* b_rho   = (const float*)d_in[7];
  const float* W1      = (const float*)d_in[8];
  const float* b1      = (const float*)d_in[9];
  const float* W2      = (const float*)d_in[10];
  const float* b2      = (const float*)d_in[11];
  char* wsc = (char*)d_ws;
  float* out = (float*)d_out;

  const _Float16* wh = (const _Float16*)(wsc + WH_OFF);
  _Float16* abh  = (_Float16*)(wsc + ABH_OFF);
  const float* bias = (const float*)(wsc + BIAS_OFF);
  const float* cmp  = (const float*)(wsc + CM_OFF);
  float* sumE  = (float*)(wsc + SUME_OFF);
  _Float16* xt = (_Float16*)(wsc + XT_OFF);
  _Float16* vt = (_Float16*)(wsc + VT_OFF);
  float* part  = out + 8388608;        // scratch in attn region (k4 overwrites later)

  hipLaunchKernelGGL(k0_setup, dim3(16), dim3(256), 0, stream,
                     cond, W_phi, b_phi, W_theta, b_theta, W_rho, b_rho,
                     W1, b1, W2, b2, wsc);
  hipLaunchKernelGGL(kT_transpose, dim3(1024), dim3(256), 0, stream, input, xt);
  hipLaunchKernelGGL(kC_main, dim3(1024), dim3(256), 0, stream,
                     xt, wh, bias, cmp, sumE, vt, (char*)(wsc + XT_OFF), part);
  hipLaunchKernelGGL(k2_reduce, dim3(128), dim3(256), 0, stream, part, sumE, abh);
  hipLaunchKernelGGL(k3_z, dim3(512), dim3(256), 0, stream, abh, vt, out);
  hipLaunchKernelGGL(k4_attn, dim3(512), dim3(256), 0, stream,
                     (const char*)(wsc + XT_OFF), sumE, out);
}